// Round 2
// baseline (558.602 us; speedup 1.0000x reference)
//
#include <hip/hip_runtime.h>

// MoE Router (Switch), fully fused — R6.
// logits = x@W + b; top-3 one-hot mask; softmax probs; importance = load = col-sum.
// x: [N=32768, D=2048] f32, W: [D, E=64] f32, b: [E] f32.
// out = [mask (N*E) | prob (N*E) | importance (E) | load (E)]  (f32)
//
// R6 (W-feed rate fix + x prefetch pipeline). R5 post-mortem: VALUBusy 22.5%
// -> ~78% stalled on W s_load latency (1 dwordx16/32cyc/wave, only ~5 in
// flight in SGPRs) + unpipelined x loads.
//   * 2 rows/lane (acc[2][16], 128 rows/block): each W scalar feeds 2 FMAs
//     -> W rate halves to 1 dwordx16/64cyc -> 5 in flight covers ~320cyc.
//   * x staging software-pipelined: chunk c+1 global loads issued before
//     compute of chunk c (T14 issue-early / write-late).
//   * BK=32, XPITCH=36 (36 == 4 mod 32: same conflict-free b128 phase
//     pattern as the verified 68 pitch; 16B-aligned).
//   * Grid 256 x 512 thr: waves = grp(K-half) x wg(16-expert slice).
//     Epilogue = R5-verified logic, x2 rows; park/cand/es regions time-share
//     the LDS with an extra barrier protecting the park region.

#define D_MODEL 2048
#define N_EXP   64
#define BK      32
#define XPITCH  36            // 36 % 32 == 4 -> conflict-free b128 phases; 16B-aligned
#define KHALF   (D_MODEL / 2)
#define ROWS    128
#define NCH     (KHALF / BK)  // 32
#define NBLK    256           // 32768 / 128 rows per block
#define PARKP   17            // padded park pitch

__device__ __forceinline__ void top3_insert16(const float* __restrict__ vv,
                                              int e0, float* __restrict__ cand) {
    // ascending-e scan + strict > == lowest-index tie-break (matches jax top_k)
    float t1 = -INFINITY, t2 = -INFINITY, t3 = -INFINITY;
    int   j1 = 0, j2 = 0, j3 = 0;
#pragma unroll
    for (int e = 0; e < 16; ++e) {
        const float xv = vv[e]; const int g = e0 + e;
        if (xv > t1)      { t3 = t2; j3 = j2; t2 = t1; j2 = j1; t1 = xv; j1 = g; }
        else if (xv > t2) { t3 = t2; j3 = j2; t2 = xv; j2 = g; }
        else if (xv > t3) { t3 = xv; j3 = g; }
    }
    cand[0] = t1; cand[1] = __int_as_float(j1);
    cand[2] = t2; cand[3] = __int_as_float(j2);
    cand[4] = t3; cand[5] = __int_as_float(j3);
}

__device__ __forceinline__ void merge12(const float* __restrict__ ldsBase,
                                        int rowIdx, float& x1,
                                        int& i1, int& i2, int& i3) {
    // candidates laid out wg-ascending == expert-ascending; linear scan with
    // strict > keeps the lowest index on ties. [R5-verified]
    float bv[12]; int bg[12];
#pragma unroll
    for (int w = 0; w < 4; ++w) {
        const float* cp = ldsBase + (size_t)(w * ROWS + rowIdx) * 8;
#pragma unroll
        for (int k = 0; k < 3; ++k) {
            bv[w * 3 + k] = cp[2 * k];
            bg[w * 3 + k] = __float_as_int(cp[2 * k + 1]);
        }
    }
#pragma unroll
    for (int pick = 0; pick < 3; ++pick) {
        float mv = bv[0]; int mg = bg[0]; int mk = 0;
#pragma unroll
        for (int k = 1; k < 12; ++k)
            if (bv[k] > mv) { mv = bv[k]; mg = bg[k]; mk = k; }
        if (pick == 0)      { x1 = mv; i1 = mg; }
        else if (pick == 1) { i2 = mg; }
        else                { i3 = mg; }
#pragma unroll
        for (int k = 0; k < 12; ++k)           // static index: stays in regs
            if (k == mk) bv[k] = -INFINITY;
    }
}

__global__ __launch_bounds__(512, 2) void fused_kernel(
    const float* __restrict__ x, const float* __restrict__ W,
    const float* __restrict__ b,
    float* __restrict__ out_mask, float* __restrict__ out_prob,
    float* __restrict__ pws) {

    __shared__ float lds[2 * ROWS * XPITCH];   // 9216 floats = 36864 B

    const int tid   = threadIdx.x;
    const int lane  = tid & 63;
    const int wv    = __builtin_amdgcn_readfirstlane(tid >> 6);  // 0..7
    const int grp   = wv >> 2;               // 0: K-half 0, 1: K-half 1
    const int wg    = wv & 3;                // expert-slice wave
    const int e0    = wg * 16;
    const int gtid  = tid & 255;
    const int rg    = blockIdx.x;            // rows rg*128 .. +127
    const int kbase = grp * KHALF;

    float* __restrict__ Xg = lds + grp * (ROWS * XPITCH);

    float acc0[16], acc1[16];
#pragma unroll
    for (int e = 0; e < 16; ++e) { acc0[e] = 0.0f; acc1[e] = 0.0f; }

    // staging map (per 256-thread group): 128 rows x 8 float4; 4 per thread
    const int srow = gtid >> 3;              // 0..31
    const int skk4 = gtid & 7;
    const float* xbase = x + (size_t)(rg * ROWS) * D_MODEL + kbase + skk4 * 4;

    float4 tmp[4];
#pragma unroll
    for (int j = 0; j < 4; ++j)
        tmp[j] = *(const float4*)(xbase + (size_t)(j * 32 + srow) * D_MODEL);

    for (int c = 0; c < NCH; ++c) {
        __syncthreads();                     // prev chunk fully consumed
#pragma unroll
        for (int j = 0; j < 4; ++j)
            *(float4*)&Xg[(j * 32 + srow) * XPITCH + skk4 * 4] = tmp[j];
        __syncthreads();
        if (c + 1 < NCH) {                   // prefetch next chunk under compute
#pragma unroll
            for (int j = 0; j < 4; ++j)
                tmp[j] = *(const float4*)(xbase + (size_t)(j * 32 + srow) * D_MODEL
                                          + (c + 1) * BK);
        }
        const float* wb = W + (size_t)(kbase + c * BK) * N_EXP + e0;
#pragma unroll
        for (int kk4 = 0; kk4 < BK / 4; ++kk4) {
            const float4 xa = *(const float4*)&Xg[lane * XPITCH + kk4 * 4];
            const float4 xc = *(const float4*)&Xg[(lane + 64) * XPITCH + kk4 * 4];
            const float* wp = wb + kk4 * 4 * N_EXP;
#pragma unroll
            for (int j = 0; j < 4; ++j) {
                const float xs0 = ((const float*)&xa)[j];
                const float xs1 = ((const float*)&xc)[j];
#pragma unroll
                for (int e = 0; e < 16; ++e) {
                    const float w = wp[j * N_EXP + e];   // s_load, wave-uniform
                    acc0[e] = fmaf(xs0, w, acc0[e]);
                    acc1[e] = fmaf(xs1, w, acc1[e]);
                }
            }
        }
    }

    __syncthreads();   // sync1: all staging-buffer reads complete

    // upper group parks partials across the whole LDS: [4][128][17]
    if (grp == 1) {
        float* d0 = lds + (size_t)(wg * ROWS + lane) * PARKP;
        float* d1 = lds + (size_t)(wg * ROWS + lane + 64) * PARKP;
#pragma unroll
        for (int e = 0; e < 16; ++e) { d0[e] = acc0[e]; d1[e] = acc1[e]; }
    }
    __syncthreads();   // sync2

    float v0[16], v1[16], pe0[16], pe1[16];
    float x1a = 0.0f, x1b = 0.0f;
    int i1a = -1, i2a = -1, i3a = -1, i1b = -1, i2b = -1, i3b = -1;

    if (grp == 0) {
        const float* s0 = lds + (size_t)(wg * ROWS + lane) * PARKP;
        const float* s1 = lds + (size_t)(wg * ROWS + lane + 64) * PARKP;
#pragma unroll
        for (int e = 0; e < 16; ++e) {
            const float be = b[e0 + e];
            v0[e] = acc0[e] + s0[e] + be;
            v1[e] = acc1[e] + s1[e] + be;
        }
    }
    __syncthreads();   // sync2b: park reads done -> region reusable for cand/es

    if (grp == 0) {
        top3_insert16(v0, e0, lds + (size_t)(wg * ROWS + lane) * 8);
        top3_insert16(v1, e0, lds + (size_t)(wg * ROWS + lane + 64) * 8);
    }
    __syncthreads();   // sync3

    if (grp == 0) {
        merge12(lds, lane,      x1a, i1a, i2a, i3a);
        merge12(lds, lane + 64, x1b, i1b, i2b, i3b);

        float esa = 0.0f, esb = 0.0f;
#pragma unroll
        for (int e = 0; e < 16; ++e) {
            pe0[e] = __expf(v0[e] - x1a); esa += pe0[e];
            pe1[e] = __expf(v1[e] - x1b); esb += pe1[e];
        }
        lds[4096 + wg * ROWS + lane]      = esa;   // es region: [4096..4607]
        lds[4096 + wg * ROWS + lane + 64] = esb;
    }
    __syncthreads();   // sync4

    if (grp == 0) {
        const float sa = lds[4096 + lane]            + lds[4096 + 128 + lane]
                       + lds[4096 + 256 + lane]      + lds[4096 + 384 + lane];
        const float sb = lds[4096 + lane + 64]       + lds[4096 + 128 + lane + 64]
                       + lds[4096 + 256 + lane + 64] + lds[4096 + 384 + lane + 64];
        const float sinva = 1.0f / sa;
        const float sinvb = 1.0f / sb;
#pragma unroll
        for (int e = 0; e < 16; ++e) { pe0[e] *= sinva; pe1[e] *= sinvb; }

        const size_t row0  = (size_t)rg * ROWS + lane;
        const size_t ob0   = row0 * N_EXP + e0;
        const size_t ob1   = (row0 + 64) * N_EXP + e0;
#pragma unroll
        for (int e4 = 0; e4 < 4; ++e4) {
            float4 pv0, mv0, pv1, mv1;
#pragma unroll
            for (int j = 0; j < 4; ++j) {
                const int g = e0 + e4 * 4 + j;
                ((float*)&pv0)[j] = pe0[e4 * 4 + j];
                ((float*)&mv0)[j] = (g == i1a || g == i2a || g == i3a) ? 1.0f : 0.0f;
                ((float*)&pv1)[j] = pe1[e4 * 4 + j];
                ((float*)&mv1)[j] = (g == i1b || g == i2b || g == i3b) ? 1.0f : 0.0f;
            }
            *(float4*)(out_prob + ob0 + e4 * 4) = pv0;
            *(float4*)(out_mask + ob0 + e4 * 4) = mv0;
            *(float4*)(out_prob + ob1 + e4 * 4) = pv1;
            *(float4*)(out_mask + ob1 + e4 * 4) = mv1;
        }

        // once-per-block column sums over all 128 rows (importance/load)
        float colAcc = 0.0f;
#pragma unroll
        for (int e = 0; e < 16; ++e) {
            float se = pe0[e] + pe1[e];
#pragma unroll
            for (int m = 32; m > 0; m >>= 1) se += __shfl_xor(se, m);
            colAcc = (lane == e) ? se : colAcc;    // static index per iter
        }
        if (lane < 16)
            pws[(size_t)(e0 + lane) * NBLK + rg] = colAcc;
    }
}

// one block per expert: sum its NBLK contiguous partials -> imp[e], load[e]
__global__ __launch_bounds__(256) void reduce_kernel(
    const float* __restrict__ pws,
    float* __restrict__ out_imp, float* __restrict__ out_load) {

    __shared__ float red[4];
    const int e   = blockIdx.x;
    const int tid = threadIdx.x;

    float s = pws[(size_t)e * NBLK + tid];   // NBLK == 256 == blockDim

#pragma unroll
    for (int m = 32; m > 0; m >>= 1) s += __shfl_xor(s, m);
    if ((tid & 63) == 0) red[tid >> 6] = s;
    __syncthreads();
    if (tid == 0) {
        const float t = red[0] + red[1] + red[2] + red[3];
        out_imp[e]  = t;
        out_load[e] = t;
    }
}

extern "C" void kernel_launch(void* const* d_in, const int* in_sizes, int n_in,
                              void* d_out, int out_size, void* d_ws, size_t ws_size,
                              hipStream_t stream) {
    const float* x = (const float*)d_in[0];
    const float* W = (const float*)d_in[1];
    const float* b = (const float*)d_in[2];

    const int N = in_sizes[0] / D_MODEL;   // 32768

    float* o        = (float*)d_out;
    float* out_mask = o;
    float* out_prob = o + (size_t)N * N_EXP;
    float* out_imp  = out_prob + (size_t)N * N_EXP;
    float* out_load = out_imp + N_EXP;

    float* pws = (float*)d_ws;             // 64 * 256 floats = 64 KB

    fused_kernel<<<N / ROWS, 512, 0, stream>>>(x, W, b, out_mask, out_prob, pws);
    reduce_kernel<<<N_EXP, 256, 0, stream>>>(pws, out_imp, out_load);
}

// Round 3
// 506.177 us; speedup vs baseline: 1.1036x; 1.1036x over previous
//
#include <hip/hip_runtime.h>

// MoE Router (Switch), fully fused — R7.
// logits = x@W + b; top-3 one-hot mask; softmax probs; importance = load = col-sum.
// x: [N=32768, D=2048] f32, W: [D, E=64] f32, b: [E] f32.
// out = [mask (N*E) | prob (N*E) | importance (E) | load (E)]  (f32)
//
// R7 (kill SMEM in the hot loop). R4/R5/R6 all pinned at VALUBusy ~20-23%:
// W fed via s_load while x comes from ds_read forces lgkmcnt(0) drains
// (SMEM returns out-of-order -> compiler can't use counted lgkmcnt when
// mixing SMEM+DS). Fix: stage W chunks into LDS (prefetch-pipelined like x)
// and read them with wave-uniform ds_read_b128 (same-address broadcast,
// conflict-free, in-order returns -> fine-grained lgkmcnt scheduling).
//   * structure otherwise identical to R6: 512 thr, grid 256, 2 rows/lane,
//     split-K groups, R5-verified top-3/softmax/merge epilogue.
//   * LDS: x 2x[128][36] (36864 B) + W 2x[32][68] (17408 B) = 54272 B.

#define D_MODEL 2048
#define N_EXP   64
#define BK      32
#define XPITCH  36            // 36 % 32 == 4 -> conflict-free b128 phases; 16B-aligned
#define WPITCH  68            // W chunk pitch (pad 64 -> 68)
#define KHALF   (D_MODEL / 2)
#define ROWS    128
#define NCH     (KHALF / BK)  // 32
#define NBLK    256           // 32768 / 128 rows per block
#define PARKP   17            // padded park pitch
#define XOFF    0
#define WOFF    (2 * ROWS * XPITCH)          // 9216 floats

__device__ __forceinline__ void top3_insert16(const float* __restrict__ vv,
                                              int e0, float* __restrict__ cand) {
    // ascending-e scan + strict > == lowest-index tie-break (matches jax top_k)
    float t1 = -INFINITY, t2 = -INFINITY, t3 = -INFINITY;
    int   j1 = 0, j2 = 0, j3 = 0;
#pragma unroll
    for (int e = 0; e < 16; ++e) {
        const float xv = vv[e]; const int g = e0 + e;
        if (xv > t1)      { t3 = t2; j3 = j2; t2 = t1; j2 = j1; t1 = xv; j1 = g; }
        else if (xv > t2) { t3 = t2; j3 = j2; t2 = xv; j2 = g; }
        else if (xv > t3) { t3 = xv; j3 = g; }
    }
    cand[0] = t1; cand[1] = __int_as_float(j1);
    cand[2] = t2; cand[3] = __int_as_float(j2);
    cand[4] = t3; cand[5] = __int_as_float(j3);
}

__device__ __forceinline__ void merge12(const float* __restrict__ ldsBase,
                                        int rowIdx, float& x1,
                                        int& i1, int& i2, int& i3) {
    // candidates laid out wg-ascending == expert-ascending; linear scan with
    // strict > keeps the lowest index on ties. [R5-verified]
    float bv[12]; int bg[12];
#pragma unroll
    for (int w = 0; w < 4; ++w) {
        const float* cp = ldsBase + (size_t)(w * ROWS + rowIdx) * 8;
#pragma unroll
        for (int k = 0; k < 3; ++k) {
            bv[w * 3 + k] = cp[2 * k];
            bg[w * 3 + k] = __float_as_int(cp[2 * k + 1]);
        }
    }
#pragma unroll
    for (int pick = 0; pick < 3; ++pick) {
        float mv = bv[0]; int mg = bg[0]; int mk = 0;
#pragma unroll
        for (int k = 1; k < 12; ++k)
            if (bv[k] > mv) { mv = bv[k]; mg = bg[k]; mk = k; }
        if (pick == 0)      { x1 = mv; i1 = mg; }
        else if (pick == 1) { i2 = mg; }
        else                { i3 = mg; }
#pragma unroll
        for (int k = 0; k < 12; ++k)           // static index: stays in regs
            if (k == mk) bv[k] = -INFINITY;
    }
}

__global__ __launch_bounds__(512, 2) void fused_kernel(
    const float* __restrict__ x, const float* __restrict__ W,
    const float* __restrict__ b,
    float* __restrict__ out_mask, float* __restrict__ out_prob,
    float* __restrict__ pws) {

    __shared__ float lds[WOFF + 2 * BK * WPITCH];   // 13568 floats = 54272 B

    const int tid   = threadIdx.x;
    const int lane  = tid & 63;
    const int wv    = __builtin_amdgcn_readfirstlane(tid >> 6);  // 0..7
    const int grp   = wv >> 2;               // 0: K-half 0, 1: K-half 1
    const int wg    = wv & 3;                // expert-slice wave
    const int e0    = wg * 16;
    const int gtid  = tid & 255;
    const int rg    = blockIdx.x;            // rows rg*128 .. +127
    const int kbase = grp * KHALF;

    float* __restrict__ Xg = lds + XOFF + grp * (ROWS * XPITCH);
    float* __restrict__ Wg = lds + WOFF + grp * (BK * WPITCH);

    float acc0[16], acc1[16];
#pragma unroll
    for (int e = 0; e < 16; ++e) { acc0[e] = 0.0f; acc1[e] = 0.0f; }

    // x staging map (per 256-thread group): 128 rows x 8 float4; 4 per thread
    const int srow = gtid >> 3;              // 0..31
    const int skk4 = gtid & 7;
    const float* xbase = x + (size_t)(rg * ROWS) * D_MODEL + kbase + skk4 * 4;

    // W staging map (per group): chunk [32 k][64 e]; 2 float4 per thread
    //   li = q*256 + gtid: k = li>>4 (0..31), e4 = li&15
    const int wk0 = gtid >> 4;               // q=0 row
    const int we4 = gtid & 15;
    const float* wgbase = W + (size_t)kbase * N_EXP + we4 * 4;

    float4 tmp[4], wtmp[2];
#pragma unroll
    for (int j = 0; j < 4; ++j)
        tmp[j] = *(const float4*)(xbase + (size_t)(j * 32 + srow) * D_MODEL);
#pragma unroll
    for (int q = 0; q < 2; ++q)
        wtmp[q] = *(const float4*)(wgbase + (size_t)(wk0 + q * 16) * N_EXP);

    for (int c = 0; c < NCH; ++c) {
        __syncthreads();                     // prev chunk fully consumed
#pragma unroll
        for (int j = 0; j < 4; ++j)
            *(float4*)&Xg[(j * 32 + srow) * XPITCH + skk4 * 4] = tmp[j];
#pragma unroll
        for (int q = 0; q < 2; ++q)
            *(float4*)&Wg[(wk0 + q * 16) * WPITCH + we4 * 4] = wtmp[q];
        __syncthreads();
        if (c + 1 < NCH) {                   // prefetch next chunk under compute
#pragma unroll
            for (int j = 0; j < 4; ++j)
                tmp[j] = *(const float4*)(xbase + (size_t)(j * 32 + srow) * D_MODEL
                                          + (c + 1) * BK);
#pragma unroll
            for (int q = 0; q < 2; ++q)
                wtmp[q] = *(const float4*)(wgbase + (size_t)(wk0 + q * 16
                                           + (c + 1) * BK) * N_EXP);
        }
#pragma unroll 2
        for (int kk4 = 0; kk4 < BK / 4; ++kk4) {
            const float4 xa = *(const float4*)&Xg[lane * XPITCH + kk4 * 4];
            const float4 xc = *(const float4*)&Xg[(lane + 64) * XPITCH + kk4 * 4];
#pragma unroll
            for (int j = 0; j < 4; ++j) {
                // wave-uniform ds_read_b128 x4: 16 W scalars, broadcast
                const float4* wrow = (const float4*)&Wg[(kk4 * 4 + j) * WPITCH + e0];
                const float4 wv0 = wrow[0], wv1 = wrow[1],
                             wv2 = wrow[2], wv3 = wrow[3];
                const float xs0 = ((const float*)&xa)[j];
                const float xs1 = ((const float*)&xc)[j];
#pragma unroll
                for (int e = 0; e < 4; ++e) {
                    const float wa = ((const float*)&wv0)[e];
                    const float wb = ((const float*)&wv1)[e];
                    const float wc = ((const float*)&wv2)[e];
                    const float wd = ((const float*)&wv3)[e];
                    acc0[e]      = fmaf(xs0, wa, acc0[e]);
                    acc1[e]      = fmaf(xs1, wa, acc1[e]);
                    acc0[e + 4]  = fmaf(xs0, wb, acc0[e + 4]);
                    acc1[e + 4]  = fmaf(xs1, wb, acc1[e + 4]);
                    acc0[e + 8]  = fmaf(xs0, wc, acc0[e + 8]);
                    acc1[e + 8]  = fmaf(xs1, wc, acc1[e + 8]);
                    acc0[e + 12] = fmaf(xs0, wd, acc0[e + 12]);
                    acc1[e + 12] = fmaf(xs1, wd, acc1[e + 12]);
                }
            }
        }
    }

    __syncthreads();   // sync1: all staging-buffer reads complete

    // upper group parks partials across the LDS: [4][128][17]
    if (grp == 1) {
        float* d0 = lds + (size_t)(wg * ROWS + lane) * PARKP;
        float* d1 = lds + (size_t)(wg * ROWS + lane + 64) * PARKP;
#pragma unroll
        for (int e = 0; e < 16; ++e) { d0[e] = acc0[e]; d1[e] = acc1[e]; }
    }
    __syncthreads();   // sync2

    float v0[16], v1[16], pe0[16], pe1[16];
    float x1a = 0.0f, x1b = 0.0f;
    int i1a = -1, i2a = -1, i3a = -1, i1b = -1, i2b = -1, i3b = -1;

    if (grp == 0) {
        const float* s0 = lds + (size_t)(wg * ROWS + lane) * PARKP;
        const float* s1 = lds + (size_t)(wg * ROWS + lane + 64) * PARKP;
#pragma unroll
        for (int e = 0; e < 16; ++e) {
            const float be = b[e0 + e];
            v0[e] = acc0[e] + s0[e] + be;
            v1[e] = acc1[e] + s1[e] + be;
        }
    }
    __syncthreads();   // sync2b: park reads done -> region reusable for cand/es

    if (grp == 0) {
        top3_insert16(v0, e0, lds + (size_t)(wg * ROWS + lane) * 8);
        top3_insert16(v1, e0, lds + (size_t)(wg * ROWS + lane + 64) * 8);
    }
    __syncthreads();   // sync3

    if (grp == 0) {
        merge12(lds, lane,      x1a, i1a, i2a, i3a);
        merge12(lds, lane + 64, x1b, i1b, i2b, i3b);

        float esa = 0.0f, esb = 0.0f;
#pragma unroll
        for (int e = 0; e < 16; ++e) {
            pe0[e] = __expf(v0[e] - x1a); esa += pe0[e];
            pe1[e] = __expf(v1[e] - x1b); esb += pe1[e];
        }
        lds[4608 + wg * ROWS + lane]      = esa;   // es region: [4608..5120)
        lds[4608 + wg * ROWS + lane + 64] = esb;
    }
    __syncthreads();   // sync4

    if (grp == 0) {
        const float sa = lds[4608 + lane]            + lds[4608 + 128 + lane]
                       + lds[4608 + 256 + lane]      + lds[4608 + 384 + lane];
        const float sb = lds[4608 + lane + 64]       + lds[4608 + 128 + lane + 64]
                       + lds[4608 + 256 + lane + 64] + lds[4608 + 384 + lane + 64];
        const float sinva = 1.0f / sa;
        const float sinvb = 1.0f / sb;
#pragma unroll
        for (int e = 0; e < 16; ++e) { pe0[e] *= sinva; pe1[e] *= sinvb; }

        const size_t row0  = (size_t)rg * ROWS + lane;
        const size_t ob0   = row0 * N_EXP + e0;
        const size_t ob1   = (row0 + 64) * N_EXP + e0;
#pragma unroll
        for (int e4 = 0; e4 < 4; ++e4) {
            float4 pv0, mv0, pv1, mv1;
#pragma unroll
            for (int j = 0; j < 4; ++j) {
                const int g = e0 + e4 * 4 + j;
                ((float*)&pv0)[j] = pe0[e4 * 4 + j];
                ((float*)&mv0)[j] = (g == i1a || g == i2a || g == i3a) ? 1.0f : 0.0f;
                ((float*)&pv1)[j] = pe1[e4 * 4 + j];
                ((float*)&mv1)[j] = (g == i1b || g == i2b || g == i3b) ? 1.0f : 0.0f;
            }
            *(float4*)(out_prob + ob0 + e4 * 4) = pv0;
            *(float4*)(out_mask + ob0 + e4 * 4) = mv0;
            *(float4*)(out_prob + ob1 + e4 * 4) = pv1;
            *(float4*)(out_mask + ob1 + e4 * 4) = mv1;
        }

        // once-per-block column sums over all 128 rows (importance/load)
        float colAcc = 0.0f;
#pragma unroll
        for (int e = 0; e < 16; ++e) {
            float se = pe0[e] + pe1[e];
#pragma unroll
            for (int m = 32; m > 0; m >>= 1) se += __shfl_xor(se, m);
            colAcc = (lane == e) ? se : colAcc;    // static index per iter
        }
        if (lane < 16)
            pws[(size_t)(e0 + lane) * NBLK + rg] = colAcc;
    }
}

// one block per expert: sum its NBLK contiguous partials -> imp[e], load[e]
__global__ __launch_bounds__(256) void reduce_kernel(
    const float* __restrict__ pws,
    float* __restrict__ out_imp, float* __restrict__ out_load) {

    __shared__ float red[4];
    const int e   = blockIdx.x;
    const int tid = threadIdx.x;

    float s = pws[(size_t)e * NBLK + tid];   // NBLK == 256 == blockDim

#pragma unroll
    for (int m = 32; m > 0; m >>= 1) s += __shfl_xor(s, m);
    if ((tid & 63) == 0) red[tid >> 6] = s;
    __syncthreads();
    if (tid == 0) {
        const float t = red[0] + red[1] + red[2] + red[3];
        out_imp[e]  = t;
        out_load[e] = t;
    }
}

extern "C" void kernel_launch(void* const* d_in, const int* in_sizes, int n_in,
                              void* d_out, int out_size, void* d_ws, size_t ws_size,
                              hipStream_t stream) {
    const float* x = (const float*)d_in[0];
    const float* W = (const float*)d_in[1];
    const float* b = (const float*)d_in[2];

    const int N = in_sizes[0] / D_MODEL;   // 32768

    float* o        = (float*)d_out;
    float* out_mask = o;
    float* out_prob = o + (size_t)N * N_EXP;
    float* out_imp  = out_prob + (size_t)N * N_EXP;
    float* out_load = out_imp + N_EXP;

    float* pws = (float*)d_ws;             // 64 * 256 floats = 64 KB

    fused_kernel<<<N / ROWS, 512, 0, stream>>>(x, W, b, out_mask, out_prob, pws);
    reduce_kernel<<<N_EXP, 256, 0, stream>>>(pws, out_imp, out_load);
}